// Round 7
// baseline (255.426 us; speedup 1.0000x reference)
//
#include <hip/hip_runtime.h>
#include <hip/hip_bf16.h>
#include <math.h>

#define NBATCH 32
#define IMGSZ  224
#define NR     400
#define NA     1024
#define ED     96

typedef __attribute__((ext_vector_type(8))) __bf16 bf16x8;
typedef __attribute__((ext_vector_type(8), aligned(8))) __bf16 bf16x8u;
typedef __attribute__((ext_vector_type(4), aligned(8))) __bf16 bf16x4a;
typedef __attribute__((ext_vector_type(4))) __bf16 bf16x4;
typedef __attribute__((ext_vector_type(4))) float f32x4;

union frag_u { struct { bf16x4a lo, hi; } p; bf16x8 v; };
union bpack  { __bf16 h[2]; unsigned u; };

// ---------------------------------------------------------------------------
// ws layout:
//   rtab    f32 [32][400]
//   costab  f32 [1024]  (pre-scaled by 223/224)
//   sintab  f32 [1024]  (pre-scaled by 223/224)
//   w2f     bf16 [20*3*6][64][8]   fragment-major w2, j^((ka+icb)&1)*4 swizzle
//   w1r     bf16 [96][64]          w1 with k' = (q*3+c)*4+ka, k' 60..63 = 0
//   xp      bf16 [32][224][224][4] channels-last packed image
//   sp      bf16 [4][32][400][3][256] sampled polar, az-quarter-major records
//           (+512 elems slack for the last garbage pair-load)
// ---------------------------------------------------------------------------

__global__ __launch_bounds__(256)
void prep_kernel(const float* __restrict__ dist,
                 const float* __restrict__ w1,
                 const float* __restrict__ w2,
                 float* __restrict__ rtab,
                 float* __restrict__ costab,
                 float* __restrict__ sintab,
                 __bf16* __restrict__ w2f,
                 __bf16* __restrict__ w1r,
                 float* __restrict__ theta_out) {
    const float PI = 3.14159265358979323846f;
    const float SC = 223.0f / 224.0f;
    int idx = blockIdx.x * 256 + threadIdx.x;

    if (idx < NBATCH * NR) {
        int b = idx / NR, i = idx % NR;
        float c0 = 0.2f + dist[b*4+0];
        float c1 = 0.2f + dist[b*4+1];
        float c2 = 0.2f + dist[b*4+2];
        float c3 = 0.2f + dist[b*4+3];
        float tmax = 0.5f * PI;
        float t  = tmax * ((float)i + 0.5f) / (float)NR;
        float t2 = t * t;
        float pt = t * (c0 + t2*(c1 + t2*(c2 + t2*c3)));
        float tm2 = tmax * tmax;
        float pm = tmax * (c0 + tm2*(c1 + tm2*(c2 + tm2*c3)));
        rtab[idx] = pt / pm * (0.5f * (float)IMGSZ);
    } else if (idx < NBATCH*NR + NA) {
        int j = idx - NBATCH*NR;
        float phi = 2.0f * PI * ((float)j + 0.5f) / (float)NA;
        costab[j] = cosf(phi) * SC;
        sintab[j] = sinf(phi) * SC;
    } else if (idx < NBATCH*NR + NA + NBATCH) {
        theta_out[idx - NBATCH*NR - NA] = 0.5f * PI;
    }

    if (idx < ED*ED*20) {
        // w2f: [(p*3+icb)*6+nt][lane][j], ic = icb*32+(lane>>4)*8+(j^sw)
        int j    = idx & 7;
        int lane = (idx >> 3) & 63;
        int grp  = idx >> 9;
        int nt   = grp % 6;
        int t    = grp / 6;
        int icb  = t % 3;
        int p    = t / 3;
        int sw   = (((p & 3) + icb) & 1) * 4;
        int oc = nt*16 + (lane & 15);
        int ic = icb*32 + (lane >> 4)*8 + (j ^ sw);
        w2f[idx] = (__bf16)w2[((size_t)(oc*ED + ic)*5 + (p >> 2))*4 + (p & 3)];
    } else if (idx < ED*ED*20 + ED*64) {
        int i2 = idx - ED*ED*20;
        int oc = i2 >> 6, k = i2 & 63;
        int rl = k >> 2, ka = k & 3;
        if (rl < 15) {
            int q = rl / 3, c = rl % 3;
            w1r[i2] = (__bf16)w1[((oc*3 + c)*5 + q)*4 + ka];
        } else {
            w1r[i2] = (__bf16)0.0f;
        }
    }
}

// x fp32 [b][c][y][x] -> xp bf16 [b][y][x][4]
__global__ __launch_bounds__(256)
void pack_image_kernel(const float* __restrict__ x, __bf16* __restrict__ xp) {
    int idx = blockIdx.x * 256 + threadIdx.x;
    if (idx >= NBATCH*IMGSZ*IMGSZ) return;
    int b  = idx / (IMGSZ*IMGSZ);
    int px = idx - b*(IMGSZ*IMGSZ);
    const float* p = x + (size_t)b*3*IMGSZ*IMGSZ + px;
    bf16x4 o;
    o[0] = (__bf16)p[0];
    o[1] = (__bf16)p[IMGSZ*IMGSZ];
    o[2] = (__bf16)p[2*IMGSZ*IMGSZ];
    o[3] = (__bf16)0.0f;
    *(bf16x4*)(xp + (size_t)idx*4) = o;
}

// ---------------------------------------------------------------------------
// Polar bilinear gather v2: block = 16 r x 64 az, thread = 2r x 2az (8 gathers
// in flight). LDS transpose -> coalesced u32 row stores into record layout
// sp[aq][b][r][c][256].
// ---------------------------------------------------------------------------
__global__ __launch_bounds__(256)
void sample_kernel(const __bf16* __restrict__ xp,
                   const float* __restrict__ rtab,
                   const float* __restrict__ costab,
                   const float* __restrict__ sintab,
                   __bf16* __restrict__ sp) {
    __shared__ unsigned sB[3][16][34];   // az-pair packed, 2-way max banks

    int tid = threadIdx.x;
    int at = blockIdx.x, rt = blockIdx.y, b = blockIdx.z;
    int w = tid >> 6, lane = tid & 63;
    int da = lane & 7;          // az-pair within wave
    int dr = lane >> 3;         // r-pair, 0..7
    int r0  = rt*16 + dr*2;
    int azl = w*16 + da*2;      // az within block
    int az0 = at*64 + azl;

    float rvs[2] = { rtab[b*NR + r0], rtab[b*NR + r0 + 1] };
    float sns[2] = { sintab[az0], sintab[az0 + 1] };
    float css[2] = { costab[az0], costab[az0 + 1] };
    const __bf16* xpb = xp + (size_t)b*IMGSZ*IMGSZ*4;

    bf16x8u p0[2][2], p1[2][2];
    float w00[2][2], w01[2][2], w10[2][2], w11[2][2];
    #pragma unroll
    for (int i = 0; i < 2; ++i) {
        #pragma unroll
        for (int j = 0; j < 2; ++j) {
            float gx = fmaf(rvs[i], sns[j], 111.5f);
            float gy = fmaf(rvs[i], css[j], 111.5f);
            float x0f = floorf(gx), y0f = floorf(gy);
            float wx1 = gx - x0f, wx0 = 1.0f - wx1;
            float wy1 = gy - y0f, wy0 = 1.0f - wy1;
            int ix = (int)x0f, iy = (int)y0f;
            ix = min(max(ix, 0), IMGSZ-2);   // always in-bounds; guard only
            iy = min(max(iy, 0), IMGSZ-2);
            const __bf16* img = xpb + ((size_t)iy*IMGSZ + ix)*4;
            p0[i][j] = *(const bf16x8u*)img;
            p1[i][j] = *(const bf16x8u*)(img + IMGSZ*4);
            w00[i][j] = wy0*wx0; w01[i][j] = wy0*wx1;
            w10[i][j] = wy1*wx0; w11[i][j] = wy1*wx1;
        }
    }
    #pragma unroll
    for (int i = 0; i < 2; ++i) {
        #pragma unroll
        for (int c = 0; c < 3; ++c) {
            float v0 = w00[i][0]*(float)p0[i][0][c] + w01[i][0]*(float)p0[i][0][4+c]
                     + w10[i][0]*(float)p1[i][0][c] + w11[i][0]*(float)p1[i][0][4+c];
            float v1 = w00[i][1]*(float)p0[i][1][c] + w01[i][1]*(float)p0[i][1][4+c]
                     + w10[i][1]*(float)p1[i][1][c] + w11[i][1]*(float)p1[i][1][4+c];
            bpack pk;
            pk.h[0] = (__bf16)v0;
            pk.h[1] = (__bf16)v1;
            sB[c][dr*2 + i][w*8 + da] = pk.u;
        }
    }
    __syncthreads();

    // store: 48 rows (c,r) of 32 u32, 2 rows per wave-store
    int rr2 = lane >> 5, azp = lane & 31;
    unsigned* sp32 = (unsigned*)sp;
    int aq = at >> 2, a32 = (at & 3)*32;
    #pragma unroll
    for (int k = 0; k < 6; ++k) {
        int pair = k*4 + w;
        int c = pair >> 3, rp8 = pair & 7;
        int r = rp8*2 + rr2;
        unsigned v = sB[c][r][azp];
        size_t rec = ((size_t)(aq*NBATCH + b)*NR + rt*16 + r)*3 + c;
        sp32[rec*128 + a32 + azp] = v;
    }
}

// ---------------------------------------------------------------------------
// conv1 (MFMA) -> t1f (conflict-free-read layout) -> conv2 (MFMA, wave =
// ka-quarter, register accumulated over kr). Staging: 8 contiguous
// global_load_lds pair-loads per kr (records are consecutive in sp).
// Block = (b, r2, az quarter aq). Grid 2048, LDS 20.5 KB.
// ---------------------------------------------------------------------------
__global__ __launch_bounds__(256, 5)
void conv_fused_kernel(const __bf16* __restrict__ sp,
                       const __bf16* __restrict__ w1r,
                       const __bf16* __restrict__ w2f,
                       const float* __restrict__ b1,
                       const float* __restrict__ b2,
                       float* __restrict__ out) {
    __shared__ __attribute__((aligned(16))) char smem[20480];
    __bf16* s_samp = (__bf16*)smem;            // [16][256] (row 15 garbage)
    __bf16* t1f    = (__bf16*)(smem + 8192);   // [12 kk][4 quad][16 m][8]
    float*  red    = (float*)smem;             // [3][16][98] at reduction

    int tid = threadIdx.x;
    int bid = blockIdx.x;                      // 2048
    int r2 = (bid ^ (bid >> 4)) & 15;          // scramble radius band
    int aq = (bid >> 4) & 3;
    int b  = bid >> 6;
    int wave = tid >> 6, lane = tid & 63, l15 = lane & 15, quad = lane >> 4;

    f32x4 acc2[6];
    #pragma unroll
    for (int nt = 0; nt < 6; ++nt) acc2[nt] = (f32x4){0.f,0.f,0.f,0.f};

    const size_t recbase = (size_t)(aq*NBATCH + b)*NR*3;

    auto stage = [&](int kr) {
        size_t rb0 = recbase + (size_t)(r2*25 + kr*5)*3;
        #pragma unroll
        for (int i = 0; i < 2; ++i) {
            int rp = wave*2 + i;                       // row-pair 0..7
            const __bf16* gp = sp + (rb0 + rp*2)*256 + lane*8;
            __builtin_amdgcn_global_load_lds(
                (const __attribute__((address_space(1))) void*)gp,
                (__attribute__((address_space(3))) void*)(s_samp + rp*512),
                16, 0, 0);
        }
    };

    stage(0);

    for (int kr = 0; kr < 5; ++kr) {
        __syncthreads();   // A: staged rows visible; prev conv2 t1f reads done

        // ---- conv1: wave = pixel-tile, pixels = wave*16 + l15
        int colb = (wave*16 + l15)*4;
        f32x4 acc1[6];
        #pragma unroll
        for (int ot = 0; ot < 6; ++ot) acc1[ot] = (f32x4){0.f,0.f,0.f,0.f};

        frag_u fa, fb;
        fa.p.lo = *(const bf16x4a*)&s_samp[(quad*2    )*256 + colb];
        fa.p.hi = *(const bf16x4a*)&s_samp[(quad*2 + 1)*256 + colb];
        fb.p.lo = *(const bf16x4a*)&s_samp[(8 + quad*2)*256 + colb];
        if (quad == 3) fb.p.hi = (bf16x4a){};
        else           fb.p.hi = *(const bf16x4a*)&s_samp[(9 + quad*2)*256 + colb];

        #pragma unroll
        for (int ot = 0; ot < 6; ++ot) {
            bf16x8 wf0 = *(const bf16x8*)(w1r + (ot*16 + l15)*64 + quad*8);
            bf16x8 wf1 = *(const bf16x8*)(w1r + (ot*16 + l15)*64 + 32 + quad*8);
            acc1[ot] = __builtin_amdgcn_mfma_f32_16x16x32_bf16(wf0, fa.v, acc1[ot], 0, 0, 0);
            acc1[ot] = __builtin_amdgcn_mfma_f32_16x16x32_bf16(wf1, fb.v, acc1[ot], 0, 0, 0);
        }

        // ---- epilogue: col=l15=pixel, row=quad*4+r=oc; scatter into t1f
        int pixel = wave*16 + l15;
        int a2l = pixel >> 2, ka = pixel & 3;
        #pragma unroll
        for (int ot = 0; ot < 6; ++ot) {
            f32x4 v = acc1[ot] + *(const f32x4*)(b1 + ot*16 + quad*4);
            bf16x4a wv;
            wv[0] = (__bf16)v[0]; wv[1] = (__bf16)v[1];
            wv[2] = (__bf16)v[2]; wv[3] = (__bf16)v[3];
            int icbase = ot*16 + quad*4;
            int kk = ka*3 + (icbase >> 5);
            int qT = (icbase >> 3) & 3;
            int jb = (icbase & 7) ^ ((kk & 1)*4);
            *(bf16x4a*)&t1f[((kk*4 + qT)*16 + a2l)*8 + jb] = wv;
        }
        __syncthreads();   // B: t1f ready; s_samp reads done

        if (kr < 4) stage(kr + 1);   // DMA overlaps conv2

        // ---- conv2: wave's ka = wave, 3 k-steps
        #pragma unroll
        for (int icb = 0; icb < 3; ++icb) {
            int kk = wave*3 + icb;
            int p  = kr*4 + wave;
            bf16x8 af = *(const bf16x8*)&t1f[(kk*64 + lane)*8];   // lane-contig
            const __bf16* wp = w2f + (size_t)((p*3 + icb)*6)*512 + lane*8;
            #pragma unroll
            for (int nt = 0; nt < 6; ++nt) {
                bf16x8 bf = *(const bf16x8*)(wp + nt*512);
                acc2[nt] = __builtin_amdgcn_mfma_f32_16x16x32_bf16(af, bf, acc2[nt], 0, 0, 0);
            }
        }
    }

    // ---- ka-quarter reduction (red aliases smem)
    __syncthreads();
    if (wave) {
        float* rw = red + (wave - 1)*1568;     // 16*98
        #pragma unroll
        for (int nt = 0; nt < 6; ++nt)
            #pragma unroll
            for (int r = 0; r < 4; ++r)
                rw[(quad*4 + r)*98 + nt*16 + l15] = acc2[nt][r];
    }
    __syncthreads();
    if (wave == 0) {
        size_t ob = ((size_t)b*1024 + r2*64 + aq*16)*ED;
        #pragma unroll
        for (int nt = 0; nt < 6; ++nt) {
            int oc = nt*16 + l15;
            float bias = b2[oc];
            #pragma unroll
            for (int r = 0; r < 4; ++r) {
                int row = quad*4 + r;
                float v = acc2[nt][r] + bias
                        + red[row*98 + oc]
                        + red[1568 + row*98 + oc]
                        + red[3136 + row*98 + oc];
                out[ob + (size_t)row*ED + oc] = v;
            }
        }
    }
}

extern "C" void kernel_launch(void* const* d_in, const int* in_sizes, int n_in,
                              void* d_out, int out_size, void* d_ws, size_t ws_size,
                              hipStream_t stream) {
    const float* x    = (const float*)d_in[0];
    const float* dist = (const float*)d_in[1];
    const float* w1   = (const float*)d_in[2];
    const float* b1   = (const float*)d_in[3];
    const float* w2   = (const float*)d_in[4];
    const float* b2   = (const float*)d_in[5];
    float* out = (float*)d_out;

    float* rtab   = (float*)d_ws;                 // 12800
    float* costab = rtab + NBATCH*NR;             // 1024
    float* sintab = costab + NA;                  // 1024
    __bf16* w2f   = (__bf16*)(sintab + NA);       // 184320 bf16
    __bf16* w1r   = w2f + ED*ED*20;               // 6144 bf16
    __bf16* xp    = w1r + ED*64;                  // 32*224*224*4 bf16
    __bf16* sp    = xp + (size_t)NBATCH*IMGSZ*IMGSZ*4;  // 4*32*400*3*256 (+slack)

    float* theta_out = out + (size_t)NBATCH*1024*ED;

    prep_kernel<<<(ED*ED*20 + ED*64 + 255)/256, 256, 0, stream>>>(
        dist, w1, w2, rtab, costab, sintab, w2f, w1r, theta_out);
    pack_image_kernel<<<(NBATCH*IMGSZ*IMGSZ + 255)/256, 256, 0, stream>>>(x, xp);
    sample_kernel<<<dim3(NA/64, NR/16, NBATCH), 256, 0, stream>>>(
        xp, rtab, costab, sintab, sp);
    conv_fused_kernel<<<NBATCH*16*4, 256, 0, stream>>>(
        sp, w1r, w2f, b1, b2, out);
}

// Round 8
// 185.658 us; speedup vs baseline: 1.3758x; 1.3758x over previous
//
#include <hip/hip_runtime.h>
#include <hip/hip_bf16.h>
#include <math.h>

#define NBATCH 32
#define IMGSZ  224
#define NR     400
#define NA     1024
#define ED     96
#define SROWE  520   // s_samp row length in elems (512 cols + 8 pad)

typedef __attribute__((ext_vector_type(8))) __bf16 bf16x8;
typedef __attribute__((ext_vector_type(8), aligned(8))) __bf16 bf16x8u;
typedef __attribute__((ext_vector_type(4), aligned(8))) __bf16 bf16x4a;
typedef __attribute__((ext_vector_type(4))) __bf16 bf16x4;
typedef __attribute__((ext_vector_type(4))) float f32x4;

union frag_u { struct { bf16x4a lo, hi; } p; bf16x8 v; };
union bpack  { __bf16 h[2]; unsigned u; };

// ---------------------------------------------------------------------------
// ws layout:
//   rtab    f32 [32][400]
//   costab  f32 [1024]  (pre-scaled by 223/224)
//   sintab  f32 [1024]  (pre-scaled by 223/224)
//   w2f     bf16 [20*3*6][64][8]   fragment-major w2, j ^ ((ka+icb)&1)*4
//   w1r     bf16 [96][64]          w1 flat [oc][k], k = (c*5+q)*4+ka, 60..63=0
//   xp      bf16 [32][224][224][4] channels-last packed image
//   sp      bf16 [32*3][400][1024] sampled polar planes (round-6 layout:
//                                  producer/consumer L2+L3 locality verified)
// ---------------------------------------------------------------------------

__global__ __launch_bounds__(256)
void prep_kernel(const float* __restrict__ dist,
                 const float* __restrict__ w1,
                 const float* __restrict__ w2,
                 float* __restrict__ rtab,
                 float* __restrict__ costab,
                 float* __restrict__ sintab,
                 __bf16* __restrict__ w2f,
                 __bf16* __restrict__ w1r,
                 float* __restrict__ theta_out) {
    const float PI = 3.14159265358979323846f;
    const float SC = 223.0f / 224.0f;
    int idx = blockIdx.x * 256 + threadIdx.x;

    if (idx < NBATCH * NR) {
        int b = idx / NR, i = idx % NR;
        float c0 = 0.2f + dist[b*4+0];
        float c1 = 0.2f + dist[b*4+1];
        float c2 = 0.2f + dist[b*4+2];
        float c3 = 0.2f + dist[b*4+3];
        float tmax = 0.5f * PI;
        float t  = tmax * ((float)i + 0.5f) / (float)NR;
        float t2 = t * t;
        float pt = t * (c0 + t2*(c1 + t2*(c2 + t2*c3)));
        float tm2 = tmax * tmax;
        float pm = tmax * (c0 + tm2*(c1 + tm2*(c2 + tm2*c3)));
        rtab[idx] = pt / pm * (0.5f * (float)IMGSZ);
    } else if (idx < NBATCH*NR + NA) {
        int j = idx - NBATCH*NR;
        float phi = 2.0f * PI * ((float)j + 0.5f) / (float)NA;
        costab[j] = cosf(phi) * SC;
        sintab[j] = sinf(phi) * SC;
    } else if (idx < NBATCH*NR + NA + NBATCH) {
        theta_out[idx - NBATCH*NR - NA] = 0.5f * PI;
    }

    if (idx < ED*ED*20) {
        // w2f: [(p*3+icb)*6+nt][lane][j], ic = icb*32+(lane>>4)*8+(j^sw)
        int j    = idx & 7;
        int lane = (idx >> 3) & 63;
        int grp  = idx >> 9;
        int nt   = grp % 6;
        int t    = grp / 6;
        int icb  = t % 3;
        int p    = t / 3;
        int sw   = (((p & 3) + icb) & 1) * 4;
        int oc = nt*16 + (lane & 15);
        int ic = icb*32 + (lane >> 4)*8 + (j ^ sw);
        w2f[idx] = (__bf16)w2[((size_t)(oc*ED + ic)*5 + (p >> 2))*4 + (p & 3)];
    } else if (idx < ED*ED*20 + ED*64) {
        int i2 = idx - ED*ED*20;
        int oc = i2 >> 6, k = i2 & 63;
        w1r[i2] = (k < 60) ? (__bf16)w1[oc*60 + k] : (__bf16)0.0f;
    }
}

// x fp32 [b][c][y][x] -> xp bf16 [b][y][x][4]
__global__ __launch_bounds__(256)
void pack_image_kernel(const float* __restrict__ x, __bf16* __restrict__ xp) {
    int idx = blockIdx.x * 256 + threadIdx.x;
    if (idx >= NBATCH*IMGSZ*IMGSZ) return;
    int b  = idx / (IMGSZ*IMGSZ);
    int px = idx - b*(IMGSZ*IMGSZ);
    const float* p = x + (size_t)b*3*IMGSZ*IMGSZ + px;
    bf16x4 o;
    o[0] = (__bf16)p[0];
    o[1] = (__bf16)p[IMGSZ*IMGSZ];
    o[2] = (__bf16)p[2*IMGSZ*IMGSZ];
    o[3] = (__bf16)0.0f;
    *(bf16x4*)(xp + (size_t)idx*4) = o;
}

// ---------------------------------------------------------------------------
// Polar bilinear gather: block = 16 r x 64 az tile, thread = 2r x 2az
// (8 gathers in flight). LDS transpose -> coalesced u32 row stores into
// plane layout sp[(b*3+c)][r][az].
// ---------------------------------------------------------------------------
__global__ __launch_bounds__(256)
void sample_kernel(const __bf16* __restrict__ xp,
                   const float* __restrict__ rtab,
                   const float* __restrict__ costab,
                   const float* __restrict__ sintab,
                   __bf16* __restrict__ sp) {
    __shared__ unsigned sB[3][16][34];

    int tid = threadIdx.x;
    int at = blockIdx.x, rt = blockIdx.y, b = blockIdx.z;
    int w = tid >> 6, lane = tid & 63;
    int da = lane & 7;
    int dr = lane >> 3;
    int r0  = rt*16 + dr*2;
    int az0 = at*64 + w*16 + da*2;

    float rvs[2] = { rtab[b*NR + r0], rtab[b*NR + r0 + 1] };
    float sns[2] = { sintab[az0], sintab[az0 + 1] };
    float css[2] = { costab[az0], costab[az0 + 1] };
    const __bf16* xpb = xp + (size_t)b*IMGSZ*IMGSZ*4;

    bf16x8u p0[2][2], p1[2][2];
    float w00[2][2], w01[2][2], w10[2][2], w11[2][2];
    #pragma unroll
    for (int i = 0; i < 2; ++i) {
        #pragma unroll
        for (int j = 0; j < 2; ++j) {
            float gx = fmaf(rvs[i], sns[j], 111.5f);
            float gy = fmaf(rvs[i], css[j], 111.5f);
            float x0f = floorf(gx), y0f = floorf(gy);
            float wx1 = gx - x0f, wx0 = 1.0f - wx1;
            float wy1 = gy - y0f, wy0 = 1.0f - wy1;
            int ix = (int)x0f, iy = (int)y0f;
            ix = min(max(ix, 0), IMGSZ-2);   // always in-bounds; guard only
            iy = min(max(iy, 0), IMGSZ-2);
            const __bf16* img = xpb + ((size_t)iy*IMGSZ + ix)*4;
            p0[i][j] = *(const bf16x8u*)img;
            p1[i][j] = *(const bf16x8u*)(img + IMGSZ*4);
            w00[i][j] = wy0*wx0; w01[i][j] = wy0*wx1;
            w10[i][j] = wy1*wx0; w11[i][j] = wy1*wx1;
        }
    }
    #pragma unroll
    for (int i = 0; i < 2; ++i) {
        #pragma unroll
        for (int c = 0; c < 3; ++c) {
            float v0 = w00[i][0]*(float)p0[i][0][c] + w01[i][0]*(float)p0[i][0][4+c]
                     + w10[i][0]*(float)p1[i][0][c] + w11[i][0]*(float)p1[i][0][4+c];
            float v1 = w00[i][1]*(float)p0[i][1][c] + w01[i][1]*(float)p0[i][1][4+c]
                     + w10[i][1]*(float)p1[i][1][c] + w11[i][1]*(float)p1[i][1][4+c];
            bpack pk;
            pk.h[0] = (__bf16)v0;
            pk.h[1] = (__bf16)v1;
            sB[c][dr*2 + i][w*8 + da] = pk.u;
        }
    }
    __syncthreads();

    // store: 48 rows (c,r) of 32 u32, coalesced into plane layout
    int rr2 = lane >> 5, azp = lane & 31;
    unsigned* sp32 = (unsigned*)sp;
    #pragma unroll
    for (int k = 0; k < 6; ++k) {
        int pair = k*4 + w;
        int c = pair >> 3, rp8 = pair & 7;
        int r = rp8*2 + rr2;
        unsigned v = sB[c][r][azp];
        size_t row = (size_t)(b*3 + c)*NR + rt*16 + r;
        sp32[row*512 + at*32 + azp] = v;
    }
}

// ---------------------------------------------------------------------------
// conv1 (MFMA) -> t1f (conflict-free layout, kk-parity swizzle) -> conv2
// (MFMA, wave = (m-tile, k-half), register-accumulated over kr).
// Staging: 15 whole-row 1024-B global_load_lds per kr (round-6 pattern).
// Block = (b, r2, azimuth half). Grid 1024, LDS 40.2 KB -> 4 blocks/CU.
// ---------------------------------------------------------------------------
__global__ __launch_bounds__(256, 4)
void conv_fused_kernel(const __bf16* __restrict__ sp,
                       const __bf16* __restrict__ w1r,
                       const __bf16* __restrict__ w2f,
                       const float* __restrict__ b1,
                       const float* __restrict__ b2,
                       float* __restrict__ out) {
    __shared__ __attribute__((aligned(16))) char smem[40192];
    __bf16* s_samp = (__bf16*)smem;             // [15][520]
    __bf16* t1f    = (__bf16*)(smem + 15616);   // [12 kk][4 quad][32 a2l][8]
    float*  red    = (float*)smem;              // [2 mt][16][97] at reduction

    int tid = threadIdx.x;
    int bid = blockIdx.x;                  // 1024
    int g   = bid >> 8;
    int r2  = (bid & 15) ^ g;              // scramble radius band across CUs
    int m4  = (bid >> 4) & 15;
    int ah  = m4 & 1;
    int b   = g*8 + (m4 >> 1);

    int wave = tid >> 6, lane = tid & 63, l15 = lane & 15, quad = lane >> 4;
    int mt = wave >> 1, kp = wave & 1;

    // conv1 weight fragments (A operand: m = oc)
    bf16x8 wfrag[2][6];
    #pragma unroll
    for (int ks = 0; ks < 2; ++ks)
        #pragma unroll
        for (int ot = 0; ot < 6; ++ot)
            wfrag[ks][ot] = *(const bf16x8*)(w1r + (ot*16 + l15)*64 + ks*32 + quad*8);

    f32x4 b1v[6];
    #pragma unroll
    for (int ot = 0; ot < 6; ++ot)
        b1v[ot] = *(const f32x4*)(b1 + ot*16 + quad*4);

    f32x4 acc2[6];
    #pragma unroll
    for (int nt = 0; nt < 6; ++nt) acc2[nt] = (f32x4){0.f,0.f,0.f,0.f};

    int rr = r2*25;

    auto stage = [&](int kr) {
        for (int ck = wave; ck < 15; ck += 4) {          // ck wave-uniform
            int c = ck / 5, q = ck - c*5;
            const __bf16* gp = sp + ((size_t)(b*3 + c)*NR + rr + kr*5 + q)*NA
                                  + ah*512 + lane*8;
            __builtin_amdgcn_global_load_lds(
                (const __attribute__((address_space(1))) void*)gp,
                (__attribute__((address_space(3))) void*)(s_samp + ck*SROWE),
                16, 0, 0);
        }
    };

    stage(0);

    for (int kr = 0; kr < 5; ++kr) {
        __syncthreads();   // A: staged rows visible; prev conv2 t1f reads done

        // ---- conv1: wave handles pixel-tiles wave*2, wave*2+1
        #pragma unroll
        for (int i = 0; i < 2; ++i) {
            int pt = wave*2 + i;
            int colb = (pt*16 + l15)*4;
            f32x4 acc1[6];
            #pragma unroll
            for (int ot = 0; ot < 6; ++ot) acc1[ot] = (f32x4){0.f,0.f,0.f,0.f};

            frag_u fa, fb;
            fa.p.lo = *(const bf16x4a*)&s_samp[(quad*2    )*SROWE + colb];
            fa.p.hi = *(const bf16x4a*)&s_samp[(quad*2 + 1)*SROWE + colb];
            fb.p.lo = *(const bf16x4a*)&s_samp[(8 + quad*2)*SROWE + colb];
            if (quad == 3) fb.p.hi = (bf16x4a){};
            else           fb.p.hi = *(const bf16x4a*)&s_samp[(9 + quad*2)*SROWE + colb];

            #pragma unroll
            for (int ot = 0; ot < 6; ++ot) {
                acc1[ot] = __builtin_amdgcn_mfma_f32_16x16x32_bf16(
                    wfrag[0][ot], fa.v, acc1[ot], 0, 0, 0);
                acc1[ot] = __builtin_amdgcn_mfma_f32_16x16x32_bf16(
                    wfrag[1][ot], fb.v, acc1[ot], 0, 0, 0);
            }

            // epilogue: col=l15 (pixel), row=quad*4+r (oc=ic); scatter to t1f
            int pixel = pt*16 + l15;
            int a2l = pixel >> 2, ka = pixel & 3;
            #pragma unroll
            for (int ot = 0; ot < 6; ++ot) {
                f32x4 v = acc1[ot] + b1v[ot];
                bf16x4a wv;
                wv[0] = (__bf16)v[0]; wv[1] = (__bf16)v[1];
                wv[2] = (__bf16)v[2]; wv[3] = (__bf16)v[3];
                int icbase = ot*16 + quad*4;
                int kk = ka*3 + (icbase >> 5);
                int qT = (icbase >> 3) & 3;
                int jb = (icbase & 7) ^ ((kk & 1)*4);
                *(bf16x4a*)&t1f[((kk*4 + qT)*32 + a2l)*8 + jb] = wv;
            }
        }
        __syncthreads();   // B: t1f ready; s_samp reads done

        if (kr < 4) stage(kr + 1);   // DMA overlaps conv2

        // ---- conv2 partial: wave = (mt, kp); 6 k-steps of its k-half
        #pragma unroll
        for (int ki = 0; ki < 6; ++ki) {
            int ka  = kp*2 + ki/3;
            int icb = ki % 3;
            int kk  = ka*3 + icb;
            int p   = kr*4 + ka;
            bf16x8 af = *(const bf16x8*)&t1f[((kk*4 + quad)*32 + mt*16 + l15)*8];
            const __bf16* wp = w2f + (size_t)((p*3 + icb)*6)*512 + lane*8;
            #pragma unroll
            for (int nt = 0; nt < 6; ++nt) {
                bf16x8 bf = *(const bf16x8*)(wp + nt*512);
                acc2[nt] = __builtin_amdgcn_mfma_f32_16x16x32_bf16(af, bf, acc2[nt], 0, 0, 0);
            }
        }
    }

    // ---- k-half reduction (red aliases s_samp region; conv2 reads only t1f)
    __syncthreads();
    if (kp) {
        #pragma unroll
        for (int nt = 0; nt < 6; ++nt)
            #pragma unroll
            for (int r = 0; r < 4; ++r)
                red[mt*1552 + (quad*4 + r)*97 + nt*16 + l15] = acc2[nt][r];
    }
    __syncthreads();
    if (!kp) {
        size_t ob = ((size_t)b*1024 + r2*64 + ah*32 + mt*16)*ED;
        #pragma unroll
        for (int nt = 0; nt < 6; ++nt) {
            int oc = nt*16 + l15;
            float bias = b2[oc];
            #pragma unroll
            for (int r = 0; r < 4; ++r) {
                float v = acc2[nt][r] + red[mt*1552 + (quad*4 + r)*97 + oc] + bias;
                out[ob + (size_t)(quad*4 + r)*ED + oc] = v;
            }
        }
    }
}

extern "C" void kernel_launch(void* const* d_in, const int* in_sizes, int n_in,
                              void* d_out, int out_size, void* d_ws, size_t ws_size,
                              hipStream_t stream) {
    const float* x    = (const float*)d_in[0];
    const float* dist = (const float*)d_in[1];
    const float* w1   = (const float*)d_in[2];
    const float* b1   = (const float*)d_in[3];
    const float* w2   = (const float*)d_in[4];
    const float* b2   = (const float*)d_in[5];
    float* out = (float*)d_out;

    float* rtab   = (float*)d_ws;                 // 12800
    float* costab = rtab + NBATCH*NR;             // 1024
    float* sintab = costab + NA;                  // 1024
    __bf16* w2f   = (__bf16*)(sintab + NA);       // 184320 bf16
    __bf16* w1r   = w2f + ED*ED*20;               // 6144 bf16
    __bf16* xp    = w1r + ED*64;                  // 32*224*224*4 bf16
    __bf16* sp    = xp + (size_t)NBATCH*IMGSZ*IMGSZ*4;  // 96*400*1024 bf16

    float* theta_out = out + (size_t)NBATCH*1024*ED;

    prep_kernel<<<(ED*ED*20 + ED*64 + 255)/256, 256, 0, stream>>>(
        dist, w1, w2, rtab, costab, sintab, w2f, w1r, theta_out);
    pack_image_kernel<<<(NBATCH*IMGSZ*IMGSZ + 255)/256, 256, 0, stream>>>(x, xp);
    sample_kernel<<<dim3(NA/64, NR/16, NBATCH), 256, 0, stream>>>(
        xp, rtab, costab, sintab, sp);
    conv_fused_kernel<<<NBATCH*16*2, 256, 0, stream>>>(
        sp, w1r, w2f, b1, b2, out);
}

// Round 9
// 142.709 us; speedup vs baseline: 1.7898x; 1.3010x over previous
//
#include <hip/hip_runtime.h>
#include <hip/hip_bf16.h>
#include <math.h>

#define NBATCH 32
#define IMGSZ  224
#define NR     400
#define NA     1024
#define ED     96
#define SROW   266   // s_samp row stride in elems (256 cols + 10; odd dword)

typedef __attribute__((ext_vector_type(8))) __bf16 bf16x8;
typedef __attribute__((ext_vector_type(8), aligned(8))) __bf16 bf16x8u;
typedef __attribute__((ext_vector_type(4), aligned(8))) __bf16 bf16x4a;
typedef __attribute__((ext_vector_type(4))) __bf16 bf16x4;
typedef __attribute__((ext_vector_type(4))) float f32x4;

union frag_u { struct { bf16x4a lo, hi; } p; bf16x8 v; };

// ---------------------------------------------------------------------------
// ws layout:
//   rtab    f32 [32][400]
//   costab  f32 [1024]  (pre-scaled by 223/224)
//   sintab  f32 [1024]  (pre-scaled by 223/224)
//   w2f     bf16 [20*3*6][64][8]  fragment-major w2, j ^ ((ka+icb)&1)*4
//   w1f     bf16 [12][64][8]      fragment-major w1 (grp = ks*6+ot), k>=60 -> 0
//   xp      bf16 [32][224][224][4] channels-last packed image
//   (no sp: sampling is fused into the conv kernel; regions are block-private)
// ---------------------------------------------------------------------------

#define PACK_N   (NBATCH*IMGSZ*IMGSZ)
#define PACK_B   ((PACK_N + 255)/256)
#define PREP_N   (ED*ED*20 + 12*64*8 + NBATCH*NR + NA + NBATCH)
#define PREP_B   ((PREP_N + 255)/256)

// merged image pack + tables + weight reorder (2-launch total pipeline)
__global__ __launch_bounds__(256)
void prep_pack_kernel(const float* __restrict__ x,
                      const float* __restrict__ dist,
                      const float* __restrict__ w1,
                      const float* __restrict__ w2,
                      __bf16* __restrict__ xp,
                      float* __restrict__ rtab,
                      float* __restrict__ costab,
                      float* __restrict__ sintab,
                      __bf16* __restrict__ w2f,
                      __bf16* __restrict__ w1f,
                      float* __restrict__ theta_out) {
    const float PI = 3.14159265358979323846f;
    const float SC = 223.0f / 224.0f;
    int bid = blockIdx.x;

    if (bid < PACK_B) {                       // ---- image pack
        int idx = bid*256 + threadIdx.x;
        if (idx >= PACK_N) return;
        int b  = idx / (IMGSZ*IMGSZ);
        int px = idx - b*(IMGSZ*IMGSZ);
        const float* p = x + (size_t)b*3*IMGSZ*IMGSZ + px;
        bf16x4 o;
        o[0] = (__bf16)p[0];
        o[1] = (__bf16)p[IMGSZ*IMGSZ];
        o[2] = (__bf16)p[2*IMGSZ*IMGSZ];
        o[3] = (__bf16)0.0f;
        *(bf16x4*)(xp + (size_t)idx*4) = o;
        return;
    }

    int idx = (bid - PACK_B)*256 + threadIdx.x;
    if (idx < ED*ED*20) {
        // w2f: [(p*3+icb)*6+nt][lane][j], ic = icb*32+(lane>>4)*8+(j^sw)
        int j    = idx & 7;
        int lane = (idx >> 3) & 63;
        int grp  = idx >> 9;
        int nt   = grp % 6;
        int t    = grp / 6;
        int icb  = t % 3;
        int p    = t / 3;
        int sw   = (((p & 3) + icb) & 1) * 4;
        int oc = nt*16 + (lane & 15);
        int ic = icb*32 + (lane >> 4)*8 + (j ^ sw);
        w2f[idx] = (__bf16)w2[((size_t)(oc*ED + ic)*5 + (p >> 2))*4 + (p & 3)];
    } else if (idx < ED*ED*20 + 12*64*8) {
        // w1f: [grp=ks*6+ot][lane][j], A-frag value w1[oc][k]
        int i2   = idx - ED*ED*20;
        int j    = i2 & 7;
        int lane = (i2 >> 3) & 63;
        int grp  = i2 >> 9;
        int ks = grp / 6, ot = grp % 6;
        int oc = ot*16 + (lane & 15);
        int k  = ks*32 + (lane >> 4)*8 + j;
        w1f[i2] = (k < 60) ? (__bf16)w1[oc*60 + k] : (__bf16)0.0f;
    } else if (idx < ED*ED*20 + 12*64*8 + NBATCH*NR) {
        int i2 = idx - ED*ED*20 - 12*64*8;
        int b = i2 / NR, i = i2 % NR;
        float c0 = 0.2f + dist[b*4+0];
        float c1 = 0.2f + dist[b*4+1];
        float c2 = 0.2f + dist[b*4+2];
        float c3 = 0.2f + dist[b*4+3];
        float tmax = 0.5f * PI;
        float t  = tmax * ((float)i + 0.5f) / (float)NR;
        float t2 = t * t;
        float pt = t * (c0 + t2*(c1 + t2*(c2 + t2*c3)));
        float tm2 = tmax * tmax;
        float pm = tmax * (c0 + tm2*(c1 + tm2*(c2 + tm2*c3)));
        rtab[i2] = pt / pm * (0.5f * (float)IMGSZ);
    } else if (idx < ED*ED*20 + 12*64*8 + NBATCH*NR + NA) {
        int j = idx - ED*ED*20 - 12*64*8 - NBATCH*NR;
        float phi = 2.0f * PI * ((float)j + 0.5f) / (float)NA;
        costab[j] = cosf(phi) * SC;
        sintab[j] = sinf(phi) * SC;
    } else if (idx < PREP_N) {
        theta_out[idx - (ED*ED*20 + 12*64*8 + NBATCH*NR + NA)] = 0.5f * PI;
    }
}

// ---------------------------------------------------------------------------
// Mega kernel: polar bilinear sample (block-private region, no sp round-trip)
// -> conv1 (MFMA, D[oc][pixel]) -> t1f (conflict-free layout) -> conv2 (MFMA,
// wave = ka-quarter, register-accumulated over kr) -> reduce -> out.
// Block = (b, aq az-quarter, r2). Grid 2048, 256 thr = 4 waves, LDS 32.6 KB.
// Per kr: [bar; conv1(kr); bar; sample(kr+1) gathers overlap conv2(kr)].
// ---------------------------------------------------------------------------
__global__ __launch_bounds__(256, 4)
void mega_kernel(const __bf16* __restrict__ xp,
                 const __bf16* __restrict__ w1f_g,
                 const __bf16* __restrict__ w2f,
                 const float* __restrict__ b1,
                 const float* __restrict__ b2,
                 const float* __restrict__ rtab,
                 const float* __restrict__ costab,
                 const float* __restrict__ sintab,
                 float* __restrict__ out) {
    __shared__ __attribute__((aligned(16))) char smem[32576];
    __bf16* s_samp = (__bf16*)smem;             // [15][266] elems 0..3989
    __bf16* t1f    = (__bf16*)(smem + 8000);    // [12 kk][4 quad][16 m][8]
    __bf16* s_w1f  = (__bf16*)(smem + 20288);   // [12 grp][64 lane][8]
    float*  red    = (float*)smem;              // [3][16][98] fp32 (aliases)

    int tid = threadIdx.x;
    int bid = blockIdx.x;                       // 2048
    int r2 = bid & 15;
    int aq = (bid >> 4) & 3;
    int b  = bid >> 6;
    int wave = tid >> 6, lane = tid & 63, l15 = lane & 15, quad = lane >> 4;

    // stage w1 fragments into LDS (12288 B, coalesced)
    #pragma unroll
    for (int i = 0; i < 3; ++i)
        *(bf16x8*)(s_w1f + i*2048 + tid*8) = *(const bf16x8*)(w1f_g + i*2048 + tid*8);

    // per-thread sampling constants: one azimuth column
    int az = aq*256 + tid;
    float sn = sintab[az];
    float cs = costab[az];
    const __bf16* xpb = xp + (size_t)b*IMGSZ*IMGSZ*4;
    const float* rb = rtab + b*NR + r2*25;

    f32x4 acc2[6];
    #pragma unroll
    for (int nt = 0; nt < 6; ++nt) acc2[nt] = (f32x4){0.f,0.f,0.f,0.f};

    // sample 5 radius rows (kr) x 3 ch into s_samp; stride-1 bf16 stores (free)
    auto sample = [&](int kr) {
        #pragma unroll
        for (int q = 0; q < 5; ++q) {
            float r  = rb[kr*5 + q];                       // wave-uniform
            float gx = fmaf(r, sn, 111.5f);
            float gy = fmaf(r, cs, 111.5f);
            float x0f = floorf(gx), y0f = floorf(gy);
            float wx1 = gx - x0f, wx0 = 1.0f - wx1;
            float wy1 = gy - y0f, wy0 = 1.0f - wy1;
            int ix = (int)x0f, iy = (int)y0f;
            ix = min(max(ix, 0), IMGSZ-2);                 // always in-bounds
            iy = min(max(iy, 0), IMGSZ-2);
            const __bf16* img = xpb + ((size_t)iy*IMGSZ + ix)*4;
            bf16x8u p0 = *(const bf16x8u*)img;
            bf16x8u p1 = *(const bf16x8u*)(img + IMGSZ*4);
            float w00 = wy0*wx0, w01 = wy0*wx1, w10 = wy1*wx0, w11 = wy1*wx1;
            #pragma unroll
            for (int c = 0; c < 3; ++c) {
                float v = w00*(float)p0[c] + w01*(float)p0[4+c]
                        + w10*(float)p1[c] + w11*(float)p1[4+c];
                s_samp[(c*5 + q)*SROW + tid] = (__bf16)v;
            }
        }
    };

    sample(0);

    for (int kr = 0; kr < 5; ++kr) {
        __syncthreads();   // A: samples(kr) visible; prev conv2 t1f reads done

        // ---- conv1: wave = pixel-tile, pixel = wave*16 + l15 in [0,64)
        int colb = (wave*16 + l15)*4;
        f32x4 acc1[6];
        #pragma unroll
        for (int ot = 0; ot < 6; ++ot) acc1[ot] = (f32x4){0.f,0.f,0.f,0.f};

        frag_u fa, fb;
        fa.p.lo = *(const bf16x4a*)&s_samp[(quad*2    )*SROW + colb];
        fa.p.hi = *(const bf16x4a*)&s_samp[(quad*2 + 1)*SROW + colb];
        fb.p.lo = *(const bf16x4a*)&s_samp[(8 + quad*2)*SROW + colb];
        if (quad == 3) fb.p.hi = (bf16x4a){};
        else           fb.p.hi = *(const bf16x4a*)&s_samp[(9 + quad*2)*SROW + colb];

        #pragma unroll
        for (int ot = 0; ot < 6; ++ot) {
            bf16x8 wf0 = *(const bf16x8*)(s_w1f + (ot     )*512 + lane*8);
            bf16x8 wf1 = *(const bf16x8*)(s_w1f + (6 + ot )*512 + lane*8);
            acc1[ot] = __builtin_amdgcn_mfma_f32_16x16x32_bf16(wf0, fa.v, acc1[ot], 0, 0, 0);
            acc1[ot] = __builtin_amdgcn_mfma_f32_16x16x32_bf16(wf1, fb.v, acc1[ot], 0, 0, 0);
        }

        // epilogue: col=l15 (pixel), row=quad*4+r (oc=ic); scatter to t1f
        int pixel = wave*16 + l15;
        int a2l = pixel >> 2, ka = pixel & 3;
        #pragma unroll
        for (int ot = 0; ot < 6; ++ot) {
            f32x4 v = acc1[ot] + *(const f32x4*)(b1 + ot*16 + quad*4);
            bf16x4a wv;
            wv[0] = (__bf16)v[0]; wv[1] = (__bf16)v[1];
            wv[2] = (__bf16)v[2]; wv[3] = (__bf16)v[3];
            int icbase = ot*16 + quad*4;
            int kk = ka*3 + (icbase >> 5);
            int qT = (icbase >> 3) & 3;
            int jb = (icbase & 7) ^ ((kk & 1)*4);
            *(bf16x4a*)&t1f[((kk*4 + qT)*16 + a2l)*8 + jb] = wv;
        }
        __syncthreads();   // B: t1f ready; s_samp reads done

        if (kr < 4) sample(kr + 1);   // gathers hide under conv2's MFMAs

        // ---- conv2: wave's ka = wave; 3 k-steps
        #pragma unroll
        for (int icb = 0; icb < 3; ++icb) {
            int kk = wave*3 + icb;
            int p  = kr*4 + wave;
            bf16x8 af = *(const bf16x8*)&t1f[(kk*64 + lane)*8];   // lane-contig
            const __bf16* wp = w2f + (size_t)((p*3 + icb)*6)*512 + lane*8;
            #pragma unroll
            for (int nt = 0; nt < 6; ++nt) {
                bf16x8 bf = *(const bf16x8*)(wp + nt*512);
                acc2[nt] = __builtin_amdgcn_mfma_f32_16x16x32_bf16(af, bf, acc2[nt], 0, 0, 0);
            }
        }
    }

    // ---- ka-quarter reduction (red aliases s_samp+t1f; w1f region untouched)
    __syncthreads();
    if (wave) {
        float* rw = red + (wave - 1)*1568;     // 16*98
        #pragma unroll
        for (int nt = 0; nt < 6; ++nt)
            #pragma unroll
            for (int r = 0; r < 4; ++r)
                rw[(quad*4 + r)*98 + nt*16 + l15] = acc2[nt][r];
    }
    __syncthreads();
    if (wave == 0) {
        size_t ob = ((size_t)b*1024 + r2*64 + aq*16)*ED;
        #pragma unroll
        for (int nt = 0; nt < 6; ++nt) {
            int oc = nt*16 + l15;
            float bias = b2[oc];
            #pragma unroll
            for (int r = 0; r < 4; ++r) {
                int row = quad*4 + r;
                float v = acc2[nt][r] + bias
                        + red[row*98 + oc]
                        + red[1568 + row*98 + oc]
                        + red[3136 + row*98 + oc];
                out[ob + (size_t)row*ED + oc] = v;
            }
        }
    }
}

extern "C" void kernel_launch(void* const* d_in, const int* in_sizes, int n_in,
                              void* d_out, int out_size, void* d_ws, size_t ws_size,
                              hipStream_t stream) {
    const float* x    = (const float*)d_in[0];
    const float* dist = (const float*)d_in[1];
    const float* w1   = (const float*)d_in[2];
    const float* b1   = (const float*)d_in[3];
    const float* w2   = (const float*)d_in[4];
    const float* b2   = (const float*)d_in[5];
    float* out = (float*)d_out;

    float* rtab   = (float*)d_ws;                 // 12800
    float* costab = rtab + NBATCH*NR;             // 1024
    float* sintab = costab + NA;                  // 1024
    __bf16* w2f   = (__bf16*)(sintab + NA);       // 184320 bf16
    __bf16* w1f   = w2f + ED*ED*20;               // 6144 bf16
    __bf16* xp    = w1f + 12*64*8;                // 32*224*224*4 bf16

    float* theta_out = out + (size_t)NBATCH*1024*ED;

    prep_pack_kernel<<<PACK_B + PREP_B, 256, 0, stream>>>(
        x, dist, w1, w2, xp, rtab, costab, sintab, w2f, w1f, theta_out);
    mega_kernel<<<NBATCH*16*4, 256, 0, stream>>>(
        xp, w1f, w2f, b1, b2, rtab, costab, sintab, out);
}

// Round 10
// 139.226 us; speedup vs baseline: 1.8346x; 1.0250x over previous
//
#include <hip/hip_runtime.h>
#include <hip/hip_bf16.h>
#include <math.h>

#define NBATCH 32
#define IMGSZ  224
#define NR     400
#define NA     1024
#define ED     96
#define SROW   266   // s_samp row stride in elems (256 cols + 10; odd dword)

typedef __attribute__((ext_vector_type(8))) __bf16 bf16x8;
typedef __attribute__((ext_vector_type(8), aligned(8))) __bf16 bf16x8u;
typedef __attribute__((ext_vector_type(4), aligned(8))) __bf16 bf16x4a;
typedef __attribute__((ext_vector_type(4))) __bf16 bf16x4;
typedef __attribute__((ext_vector_type(4))) float f32x4;

union frag_u { struct { bf16x4a lo, hi; } p; bf16x8 v; };

// ---------------------------------------------------------------------------
// ws layout:
//   rtab    f32 [32][400]
//   costab  f32 [1024]  (pre-scaled by 223/224)
//   sintab  f32 [1024]  (pre-scaled by 223/224)
//   w2f     bf16 [20*3*6][64][8]  fragment-major w2, j ^ ((ka+icb)&1)*4
//   w1f     bf16 [12][64][8]      fragment-major w1 (grp = ks*6+ot), k>=60 -> 0
//   xp      bf16 [32][224][224][4] channels-last packed image
// ---------------------------------------------------------------------------

#define PACK_N   (NBATCH*IMGSZ*IMGSZ)
#define PACK_B   ((PACK_N + 255)/256)
#define PREP_N   (ED*ED*20 + 12*64*8 + NBATCH*NR + NA + NBATCH)
#define PREP_B   ((PREP_N + 255)/256)

// merged image pack + tables + weight reorder (2-launch total pipeline)
__global__ __launch_bounds__(256)
void prep_pack_kernel(const float* __restrict__ x,
                      const float* __restrict__ dist,
                      const float* __restrict__ w1,
                      const float* __restrict__ w2,
                      __bf16* __restrict__ xp,
                      float* __restrict__ rtab,
                      float* __restrict__ costab,
                      float* __restrict__ sintab,
                      __bf16* __restrict__ w2f,
                      __bf16* __restrict__ w1f,
                      float* __restrict__ theta_out) {
    const float PI = 3.14159265358979323846f;
    const float SC = 223.0f / 224.0f;
    int bid = blockIdx.x;

    if (bid < PACK_B) {                       // ---- image pack
        int idx = bid*256 + threadIdx.x;
        if (idx >= PACK_N) return;
        int b  = idx / (IMGSZ*IMGSZ);
        int px = idx - b*(IMGSZ*IMGSZ);
        const float* p = x + (size_t)b*3*IMGSZ*IMGSZ + px;
        bf16x4 o;
        o[0] = (__bf16)p[0];
        o[1] = (__bf16)p[IMGSZ*IMGSZ];
        o[2] = (__bf16)p[2*IMGSZ*IMGSZ];
        o[3] = (__bf16)0.0f;
        *(bf16x4*)(xp + (size_t)idx*4) = o;
        return;
    }

    int idx = (bid - PACK_B)*256 + threadIdx.x;
    if (idx < ED*ED*20) {
        // w2f: [(p*3+icb)*6+nt][lane][j], ic = icb*32+(lane>>4)*8+(j^sw)
        int j    = idx & 7;
        int lane = (idx >> 3) & 63;
        int grp  = idx >> 9;
        int nt   = grp % 6;
        int t    = grp / 6;
        int icb  = t % 3;
        int p    = t / 3;
        int sw   = (((p & 3) + icb) & 1) * 4;
        int oc = nt*16 + (lane & 15);
        int ic = icb*32 + (lane >> 4)*8 + (j ^ sw);
        w2f[idx] = (__bf16)w2[((size_t)(oc*ED + ic)*5 + (p >> 2))*4 + (p & 3)];
    } else if (idx < ED*ED*20 + 12*64*8) {
        // w1f: [grp=ks*6+ot][lane][j], A-frag value w1[oc][k]
        int i2   = idx - ED*ED*20;
        int j    = i2 & 7;
        int lane = (i2 >> 3) & 63;
        int grp  = i2 >> 9;
        int ks = grp / 6, ot = grp % 6;
        int oc = ot*16 + (lane & 15);
        int k  = ks*32 + (lane >> 4)*8 + j;
        w1f[i2] = (k < 60) ? (__bf16)w1[oc*60 + k] : (__bf16)0.0f;
    } else if (idx < ED*ED*20 + 12*64*8 + NBATCH*NR) {
        int i2 = idx - ED*ED*20 - 12*64*8;
        int b = i2 / NR, i = i2 % NR;
        float c0 = 0.2f + dist[b*4+0];
        float c1 = 0.2f + dist[b*4+1];
        float c2 = 0.2f + dist[b*4+2];
        float c3 = 0.2f + dist[b*4+3];
        float tmax = 0.5f * PI;
        float t  = tmax * ((float)i + 0.5f) / (float)NR;
        float t2 = t * t;
        float pt = t * (c0 + t2*(c1 + t2*(c2 + t2*c3)));
        float tm2 = tmax * tmax;
        float pm = tmax * (c0 + tm2*(c1 + tm2*(c2 + tm2*c3)));
        rtab[i2] = pt / pm * (0.5f * (float)IMGSZ);
    } else if (idx < ED*ED*20 + 12*64*8 + NBATCH*NR + NA) {
        int j = idx - ED*ED*20 - 12*64*8 - NBATCH*NR;
        float phi = 2.0f * PI * ((float)j + 0.5f) / (float)NA;
        costab[j] = cosf(phi) * SC;
        sintab[j] = sinf(phi) * SC;
    } else if (idx < PREP_N) {
        theta_out[idx - (ED*ED*20 + 12*64*8 + NBATCH*NR + NA)] = 0.5f * PI;
    }
}

// ---------------------------------------------------------------------------
// Mega kernel: polar bilinear sample (block-private region) -> conv1 (MFMA,
// D[oc][pixel]) -> t1f (conflict-free layout) -> conv2 (MFMA, wave =
// ka-quarter, register-accumulated over kr) -> reduce -> out.
// Block = (b, aq az-quarter, r2). Grid 2048, 256 thr = 4 waves, LDS 31.8 KB.
// Loop body order: conv1 | bar | conv2 | sched_barrier | sample(kr+1) —
// so conv2's vmcnt waits never drain the sample gathers (in-order FIFO).
// ---------------------------------------------------------------------------
__global__ __launch_bounds__(256, 4)
void mega_kernel(const __bf16* __restrict__ xp,
                 const __bf16* __restrict__ w1f_g,
                 const __bf16* __restrict__ w2f,
                 const float* __restrict__ b1,
                 const float* __restrict__ b2,
                 const float* __restrict__ rtab,
                 const float* __restrict__ costab,
                 const float* __restrict__ sintab,
                 float* __restrict__ out) {
    __shared__ __attribute__((aligned(16))) char smem[32576];
    __bf16* s_samp = (__bf16*)smem;             // [15][266] elems 0..3989
    __bf16* t1f    = (__bf16*)(smem + 8000);    // [12 kk][4 quad][16 m][8]
    __bf16* s_w1f  = (__bf16*)(smem + 20288);   // [12 grp][64 lane][8]
    float*  red    = (float*)smem;              // [3][16][98] fp32 (aliases)

    int tid = threadIdx.x;
    int bid = blockIdx.x;                       // 2048
    int r2 = bid & 15;
    int aq = (bid >> 4) & 3;
    int b  = bid >> 6;
    int wave = tid >> 6, lane = tid & 63, l15 = lane & 15, quad = lane >> 4;

    // stage w1 fragments into LDS (12288 B, coalesced)
    #pragma unroll
    for (int i = 0; i < 3; ++i)
        *(bf16x8*)(s_w1f + i*2048 + tid*8) = *(const bf16x8*)(w1f_g + i*2048 + tid*8);

    // per-thread sampling constants: one azimuth column
    int az = aq*256 + tid;
    float sn = sintab[az];
    float cs = costab[az];
    const __bf16* xpb = xp + (size_t)b*IMGSZ*IMGSZ*4;
    const float* rb = rtab + b*NR + r2*25;

    f32x4 acc2[6];
    #pragma unroll
    for (int nt = 0; nt < 6; ++nt) acc2[nt] = (f32x4){0.f,0.f,0.f,0.f};

    // sample 5 radius rows (kr) x 3 ch into s_samp; stride-1 bf16 stores (free)
    auto sample = [&](int kr) {
        #pragma unroll
        for (int q = 0; q < 5; ++q) {
            float r  = rb[kr*5 + q];                       // wave-uniform
            float gx = fmaf(r, sn, 111.5f);
            float gy = fmaf(r, cs, 111.5f);
            float x0f = floorf(gx), y0f = floorf(gy);
            float wx1 = gx - x0f, wx0 = 1.0f - wx1;
            float wy1 = gy - y0f, wy0 = 1.0f - wy1;
            int ix = (int)x0f, iy = (int)y0f;
            ix = min(max(ix, 0), IMGSZ-2);                 // always in-bounds
            iy = min(max(iy, 0), IMGSZ-2);
            const __bf16* img = xpb + ((size_t)iy*IMGSZ + ix)*4;
            bf16x8u p0 = *(const bf16x8u*)img;
            bf16x8u p1 = *(const bf16x8u*)(img + IMGSZ*4);
            float w00 = wy0*wx0, w01 = wy0*wx1, w10 = wy1*wx0, w11 = wy1*wx1;
            #pragma unroll
            for (int c = 0; c < 3; ++c) {
                float v = w00*(float)p0[c] + w01*(float)p0[4+c]
                        + w10*(float)p1[c] + w11*(float)p1[4+c];
                s_samp[(c*5 + q)*SROW + tid] = (__bf16)v;
            }
        }
    };

    sample(0);

    for (int kr = 0; kr < 5; ++kr) {
        __syncthreads();   // A: samples(kr) visible; prev conv2 t1f reads done

        // ---- conv1: wave = pixel-tile, pixel = wave*16 + l15 in [0,64)
        int colb = (wave*16 + l15)*4;
        f32x4 acc1[6];
        #pragma unroll
        for (int ot = 0; ot < 6; ++ot) acc1[ot] = (f32x4){0.f,0.f,0.f,0.f};

        frag_u fa, fb;
        fa.p.lo = *(const bf16x4a*)&s_samp[(quad*2    )*SROW + colb];
        fa.p.hi = *(const bf16x4a*)&s_samp[(quad*2 + 1)*SROW + colb];
        fb.p.lo = *(const bf16x4a*)&s_samp[(8 + quad*2)*SROW + colb];
        if (quad == 3) fb.p.hi = (bf16x4a){};
        else           fb.p.hi = *(const bf16x4a*)&s_samp[(9 + quad*2)*SROW + colb];

        #pragma unroll
        for (int ot = 0; ot < 6; ++ot) {
            bf16x8 wf0 = *(const bf16x8*)(s_w1f + (ot     )*512 + lane*8);
            bf16x8 wf1 = *(const bf16x8*)(s_w1f + (6 + ot )*512 + lane*8);
            acc1[ot] = __builtin_amdgcn_mfma_f32_16x16x32_bf16(wf0, fa.v, acc1[ot], 0, 0, 0);
            acc1[ot] = __builtin_amdgcn_mfma_f32_16x16x32_bf16(wf1, fb.v, acc1[ot], 0, 0, 0);
        }

        // epilogue: col=l15 (pixel), row=quad*4+r (oc=ic); scatter to t1f
        int pixel = wave*16 + l15;
        int a2l = pixel >> 2, ka = pixel & 3;
        #pragma unroll
        for (int ot = 0; ot < 6; ++ot) {
            f32x4 v = acc1[ot] + *(const f32x4*)(b1 + ot*16 + quad*4);
            bf16x4a wv;
            wv[0] = (__bf16)v[0]; wv[1] = (__bf16)v[1];
            wv[2] = (__bf16)v[2]; wv[3] = (__bf16)v[3];
            int icbase = ot*16 + quad*4;
            int kk = ka*3 + (icbase >> 5);
            int qT = (icbase >> 3) & 3;
            int jb = (icbase & 7) ^ ((kk & 1)*4);
            *(bf16x4a*)&t1f[((kk*4 + qT)*16 + a2l)*8 + jb] = wv;
        }
        __syncthreads();   // B: t1f ready; s_samp reads done

        // ---- conv2 FIRST: wave's ka = wave; 3 k-steps (vm loads self-owned)
        #pragma unroll
        for (int icb = 0; icb < 3; ++icb) {
            int kk = wave*3 + icb;
            int p  = kr*4 + wave;
            bf16x8 af = *(const bf16x8*)&t1f[(kk*64 + lane)*8];   // lane-contig
            const __bf16* wp = w2f + (size_t)((p*3 + icb)*6)*512 + lane*8;
            #pragma unroll
            for (int nt = 0; nt < 6; ++nt) {
                bf16x8 bf = *(const bf16x8*)(wp + nt*512);
                acc2[nt] = __builtin_amdgcn_mfma_f32_16x16x32_bf16(af, bf, acc2[nt], 0, 0, 0);
            }
        }

        // keep sample's gathers AFTER conv2's loads (vmcnt FIFO ordering)
        __builtin_amdgcn_sched_barrier(0);

        if (kr < 4) sample(kr + 1);   // gather latency hidden by other waves
    }

    // ---- ka-quarter reduction (red aliases s_samp+t1f; w1f region untouched)
    __syncthreads();
    if (wave) {
        float* rw = red + (wave - 1)*1568;     // 16*98
        #pragma unroll
        for (int nt = 0; nt < 6; ++nt)
            #pragma unroll
            for (int r = 0; r < 4; ++r)
                rw[(quad*4 + r)*98 + nt*16 + l15] = acc2[nt][r];
    }
    __syncthreads();
    if (wave == 0) {
        size_t ob = ((size_t)b*1024 + r2*64 + aq*16)*ED;
        #pragma unroll
        for (int nt = 0; nt < 6; ++nt) {
            int oc = nt*16 + l15;
            float bias = b2[oc];
            #pragma unroll
            for (int r = 0; r < 4; ++r) {
                int row = quad*4 + r;
                float v = acc2[nt][r] + bias
                        + red[row*98 + oc]
                        + red[1568 + row*98 + oc]
                        + red[3136 + row*98 + oc];
                out[ob + (size_t)row*ED + oc] = v;
            }
        }
    }
}

extern "C" void kernel_launch(void* const* d_in, const int* in_sizes, int n_in,
                              void* d_out, int out_size, void* d_ws, size_t ws_size,
                              hipStream_t stream) {
    const float* x    = (const float*)d_in[0];
    const float* dist = (const float*)d_in[1];
    const float* w1   = (const float*)d_in[2];
    const float* b1   = (const float*)d_in[3];
    const float* w2   = (const float*)d_in[4];
    const float* b2   = (const float*)d_in[5];
    float* out = (float*)d_out;

    float* rtab   = (float*)d_ws;                 // 12800
    float* costab = rtab + NBATCH*NR;             // 1024
    float* sintab = costab + NA;                  // 1024
    __bf16* w2f   = (__bf16*)(sintab + NA);       // 184320 bf16
    __bf16* w1f   = w2f + ED*ED*20;               // 6144 bf16
    __bf16* xp    = w1f + 12*64*8;                // 32*224*224*4 bf16

    float* theta_out = out + (size_t)NBATCH*1024*ED;

    prep_pack_kernel<<<PACK_B + PREP_B, 256, 0, stream>>>(
        x, dist, w1, w2, xp, rtab, costab, sintab, w2f, w1f, theta_out);
    mega_kernel<<<NBATCH*16*4, 256, 0, stream>>>(
        xp, w1f, w2f, b1, b2, rtab, costab, sintab, out);
}